// Round 9
// baseline (742.111 us; speedup 1.0000x reference)
//
#include <hip/hip_runtime.h>

#define H 128

__device__ __forceinline__ float bf2f(unsigned short u) {
    return __uint_as_float(((unsigned)u) << 16);
}
__device__ __forceinline__ unsigned short f2bf(float f) {
    unsigned u = __float_as_uint(f);
    unsigned r = (u + 0x7fffu + ((u >> 16) & 1u)) >> 16;
    return (unsigned short)r;
}

__global__ void fill_u32(unsigned* __restrict__ p, unsigned v, int n) {
    int i = blockIdx.x * blockDim.x + threadIdx.x;
    if (i < n) p[i] = v;
}

// ---------------- fuse: 64-node tile, lane=node, wave-uniform weights ----------------
__global__ void fuse_kernel(const float* __restrict__ x,
                            const float* __restrict__ sat_w, const float* __restrict__ sat_b,
                            const float* __restrict__ neigh_w, const float* __restrict__ neigh_b,
                            const float* __restrict__ fus_w, const float* __restrict__ fus_b,
                            float* __restrict__ h0, int N) {
    __shared__ float xs[64 * 68];    // 64 nodes x 64 inputs, pad 68
    __shared__ float outs[64 * 132]; // 64 nodes x 128 outputs, pad 132
    __shared__ float reds[4][64];
    int tid = threadIdx.x;
    int base = blockIdx.x * 64;
    for (int i = tid; i < 64 * 64; i += 256) {
        int n = i >> 6, k = i & 63;
        int gn = base + n;
        xs[n * 68 + k] = (gn < N) ? x[(size_t)gn * 64 + k] : 0.f;
    }
    __syncthreads();
    int lane = tid & 63; // node within tile
    int wv = __builtin_amdgcn_readfirstlane(tid >> 6); // feature quarter (uniform)
    // x row into registers (aligned float4 LDS reads)
    float xa[32], xb[32];
#pragma unroll
    for (int i = 0; i < 32; i += 4) {
        *(float4*)&xa[i] = *(const float4*)&xs[lane * 68 + i];
        *(float4*)&xb[i] = *(const float4*)&xs[lane * 68 + 32 + i];
    }
    float sat[32], nei[32];
    float part = 0.f;
#pragma unroll
    for (int f = 0; f < 32; ++f) {
        int gf = wv * 32 + f;
        const float* swr = sat_w + (size_t)gf * 32;   // wave-uniform
        const float* nwr = neigh_w + (size_t)gf * 32; // wave-uniform
        float a = sat_b[gf], b = neigh_b[gf];
#pragma unroll
        for (int k = 0; k < 32; ++k) {
            a += xa[k] * swr[k];
            b += xb[k] * nwr[k];
        }
        a = fmaxf(a, 0.f);
        b = fmaxf(b, 0.f);
        sat[f] = a;
        nei[f] = b;
        part += a * fus_w[gf] + b * fus_w[128 + gf];
    }
    reds[wv][lane] = part;
    __syncthreads();
    float tot = reds[0][lane] + reds[1][lane] + reds[2][lane] + reds[3][lane];
    float g = 1.f / (1.f + __expf(-(tot + fus_b[0])));
#pragma unroll
    for (int f = 0; f < 32; ++f) {
        outs[lane * 132 + wv * 32 + f] = g * sat[f] + (1.f - g) * nei[f];
    }
    __syncthreads();
    for (int i = tid; i < 64 * 128; i += 256) {
        int n = i >> 7, k = i & 127;
        int gn = base + n;
        if (gn < N) h0[(size_t)gn * H + k] = outs[n * 132 + k];
    }
}

// ---------------- 128x128 GEMM: kc-outer, 32 live accumulators ----------------
template <int TAG, int OBF16>
__global__ void gemm128(const float* __restrict__ in, const float* __restrict__ w,
                        const float* __restrict__ bias, int do_relu,
                        void* __restrict__ outv, int N,
                        const float* __restrict__ a_sp, const float* __restrict__ a_dp,
                        float* __restrict__ al_s, float* __restrict__ al_d) {
    __shared__ float xl[64 * 132]; // pad 132: float4-aligned, 8-lane bank coverage
    __shared__ float reds[4][64];
    __shared__ float redd[4][64];
    int tid = threadIdx.x;
    int base = blockIdx.x * 64;
    for (int i = tid; i < 64 * 128; i += 256) {
        int n = i >> 7, k = i & 127;
        int gn = base + n;
        xl[n * 132 + k] = (gn < N) ? in[(size_t)gn * 128 + k] : 0.f;
    }
    __syncthreads();
    int lane = tid & 63;
    int wv = __builtin_amdgcn_readfirstlane(tid >> 6);
    int xb = lane * 132;
    float acc[32];
#pragma unroll
    for (int c = 0; c < 32; ++c) acc[c] = 0.f;
    const float* w0 = w + (size_t)(wv * 32) * 128;
    for (int kc = 0; kc < 128; kc += 16) {
        float xv[16];
#pragma unroll
        for (int i = 0; i < 16; i += 4) *(float4*)&xv[i] = *(const float4*)&xl[xb + kc + i];
#pragma unroll
        for (int j = 0; j < 32; ++j) {
            const float* wr = w0 + (size_t)j * 128 + kc; // wave-uniform contiguous 16
#pragma unroll
            for (int i = 0; i < 16; ++i) acc[j] += xv[i] * wr[i];
        }
    }
#pragma unroll
    for (int j = 0; j < 32; ++j) {
        float v = acc[j] + (bias ? bias[wv * 32 + j] : 0.f);
        if (do_relu) v = fmaxf(v, 0.f);
        acc[j] = v;
    }
    __syncthreads();
#pragma unroll
    for (int j = 0; j < 32; j += 4) *(float4*)&xl[xb + wv * 32 + j] = *(float4*)&acc[j];
    __syncthreads();
    for (int i = tid; i < 64 * 128; i += 256) {
        int n = i >> 7, k = i & 127;
        int gn = base + n;
        if (gn < N) {
            if (OBF16) ((unsigned short*)outv)[(size_t)gn * H + k] = f2bf(xl[n * 132 + k]);
            else       ((float*)outv)[(size_t)gn * H + k] = xl[n * 132 + k];
        }
    }
    if (a_sp) {
        int node = tid & 63;
        int part = tid >> 6;
        float ps = 0.f, pd = 0.f;
        int kb = part * 32;
        const float* xr = xl + node * 132 + kb;
#pragma unroll
        for (int k = 0; k < 32; ++k) {
            float v = xr[k];
            ps += v * a_sp[kb + k];
            pd += v * a_dp[kb + k];
        }
        reds[part][node] = ps;
        redd[part][node] = pd;
        __syncthreads();
        if (tid < 64) {
            int gn = base + tid;
            if (gn < N) {
                al_s[gn] = reds[0][tid] + reds[1][tid] + reds[2][tid] + reds[3][tid];
                al_d[gn] = redd[0][tid] + redd[1][tid] + redd[2][tid] + redd[3][tid];
            }
        }
    }
}

// ---------------- CSR build with XCD-ownership ----------------
#define SCB 256
__global__ void hist8(const int* __restrict__ dst, int* __restrict__ cnt, int E, int N) {
    int g = blockIdx.x & 7;
    int chunk = blockIdx.x >> 3;
    int nch = gridDim.x >> 3;
    int NR = (N + 7) >> 3;
    int lo = g * NR;
    int hi = min(lo + NR, N);
    for (int e = chunk * SCB + threadIdx.x; e < E; e += nch * SCB) {
        int d = dst[e];
        if (d >= lo && d < hi) atomicAdd(cnt + d, 1);
    }
}

__global__ void scan_a(const int* __restrict__ cnt, int* __restrict__ nodeoff,
                       int* __restrict__ blocksum, int N) {
    int i = blockIdx.x * SCB + threadIdx.x;
    int tot = (i < N) ? cnt[i] : 0;
    __shared__ int tmp[SCB];
    tmp[threadIdx.x] = tot;
    __syncthreads();
    for (int off = 1; off < SCB; off <<= 1) {
        int t = (threadIdx.x >= off) ? tmp[threadIdx.x - off] : 0;
        __syncthreads();
        tmp[threadIdx.x] += t;
        __syncthreads();
    }
    if (i < N) nodeoff[i] = tmp[threadIdx.x] - tot;
    if (threadIdx.x == SCB - 1) blocksum[blockIdx.x] = tmp[SCB - 1];
}

__global__ void scan_b(const int* __restrict__ blocksum, int* __restrict__ blockoff,
                       int* __restrict__ rowptrN, int NB) {
    __shared__ int tmp[1024];
    int t = threadIdx.x;
    int v = (t < NB) ? blocksum[t] : 0;
    tmp[t] = v;
    __syncthreads();
    for (int off = 1; off < 1024; off <<= 1) {
        int u = (t >= off) ? tmp[t - off] : 0;
        __syncthreads();
        tmp[t] += u;
        __syncthreads();
    }
    if (t < NB) blockoff[t] = tmp[t] - v;
    if (t == 1023) *rowptrN = tmp[1023];
}

__global__ void scan_c(const int* __restrict__ nodeoff, const int* __restrict__ blockoff,
                       int* __restrict__ rowptr, int* __restrict__ cursor,
                       float* __restrict__ accum2, int N) {
    if (blockIdx.x < 2) {
        accum2[blockIdx.x * 256 + threadIdx.x] = 0.f;
    }
    int i = blockIdx.x * SCB + threadIdx.x;
    if (i >= N) return;
    int run = blockoff[blockIdx.x] + nodeoff[i];
    rowptr[i] = run;
    cursor[i] = run;
}

__global__ void scatter8(const int* __restrict__ src, const int* __restrict__ dst,
                         int* __restrict__ cursor, int* __restrict__ ssrc, int E, int N) {
    int g = blockIdx.x & 7;
    int chunk = blockIdx.x >> 3;
    int nch = gridDim.x >> 3;
    int NR = (N + 7) >> 3;
    int lo = g * NR;
    int hi = min(lo + NR, N);
    for (int e = chunk * SCB + threadIdx.x; e < E; e += nch * SCB) {
        int d = dst[e];
        if (d >= lo && d < hi) {
            int pos = atomicAdd(cursor + d, 1);
            ssrc[pos] = src[e];
        }
    }
}

// ---------------- GAT aggregation: one wave per dst node, bf16 h ----------------
#define PF 8
template <int TAG>
__global__ void gat_agg(const int* __restrict__ rowptr, const int* __restrict__ ssrc,
                        const float* __restrict__ al_s, const float* __restrict__ al_d,
                        const unsigned short* __restrict__ hb, float* __restrict__ out, int N) {
    __shared__ int s_sv[4][64];
    __shared__ float s_ev[4][64];
    int wiw = threadIdx.x >> 6;
    int w = (blockIdx.x * blockDim.x + threadIdx.x) >> 6;
    int lane = threadIdx.x & 63;
    if (w >= N) return;
    int beg = rowptr[w], end = rowptr[w + 1];
    float ald = al_d[w];
    float a_self = al_s[w] + ald;
    a_self = (a_self > 0.f) ? a_self : 0.2f * a_self;
    float m = a_self;
    for (int e = beg + lane; e < end; e += 64) {
        float a = al_s[ssrc[e]] + ald;
        a = (a > 0.f) ? a : 0.2f * a;
        m = fmaxf(m, a);
    }
    for (int off = 32; off; off >>= 1) m = fmaxf(m, __shfl_xor(m, off));
    float ss = 0.f, acc0 = 0.f, acc1 = 0.f;
    for (int base = beg; base < end; base += 64) {
        int nch = min(64, end - base);
        int sv = 0;
        float ev = 0.f;
        if (lane < nch) {
            sv = ssrc[base + lane];
            float a = al_s[sv] + ald;
            a = (a > 0.f) ? a : 0.2f * a;
            ev = __expf(a - m);
        }
        ss += ev;
        s_sv[wiw][lane] = sv;
        s_ev[wiw][lane] = ev;
        for (int j0 = 0; j0 < nch; j0 += PF) {
            int np = min(PF, nch - j0);
            ushort2 hv[PF];
#pragma unroll
            for (int jj = 0; jj < PF; ++jj) {
                if (jj < np) {
                    int svj = s_sv[wiw][j0 + jj];
                    hv[jj] = ((const ushort2*)(hb + (size_t)svj * H))[lane];
                }
            }
#pragma unroll
            for (int jj = 0; jj < PF; ++jj) {
                if (jj < np) {
                    float evj = s_ev[wiw][j0 + jj];
                    acc0 += evj * bf2f(hv[jj].x);
                    acc1 += evj * bf2f(hv[jj].y);
                }
            }
        }
    }
    for (int off = 32; off; off >>= 1) ss += __shfl_xor(ss, off);
    float ev_self = __expf(a_self - m);
    ss += ev_self;
    ushort2 hs = ((const ushort2*)(hb + (size_t)w * H))[lane];
    acc0 += ev_self * bf2f(hs.x);
    acc1 += ev_self * bf2f(hs.y);
    float inv = 1.f / (ss + 1e-16f);
    ((float2*)(out + (size_t)w * H))[lane] = make_float2(acc0 * inv, acc1 * inv);
}

// ---------------- BN stats ----------------
__global__ void bn_stats(const float* __restrict__ y, float* __restrict__ accum, int N) {
    int f = threadIdx.x & 127;
    int half = threadIdx.x >> 7;
    float sum = 0.f, sumsq = 0.f;
    for (int n = blockIdx.x * 2 + half; n < N; n += gridDim.x * 2) {
        float v = y[(size_t)n * H + f];
        sum += v;
        sumsq += v * v;
    }
    __shared__ float ls[2][128], ls2[2][128];
    ls[half][f] = sum;
    ls2[half][f] = sumsq;
    __syncthreads();
    if (half == 0) {
        atomicAdd(accum + f, ls[0][f] + ls[1][f]);
        atomicAdd(accum + 128 + f, ls2[0][f] + ls2[1][f]);
    }
}

// ---------------- BN apply + relu + residual ----------------
__global__ void bn_apply(float* __restrict__ y, const float* __restrict__ accum,
                         const float* __restrict__ g, const float* __restrict__ be,
                         const float* __restrict__ res, int N) {
    int i = blockIdx.x * blockDim.x + threadIdx.x;
    if (i >= N * H) return;
    int f = i & 127;
    float Ninv = 1.f / (float)N;
    float mu = accum[f] * Ninv;
    float var = accum[128 + f] * Ninv - mu * mu;
    float v = (y[i] - mu) * rsqrtf(var + 1e-5f) * g[f] + be[f];
    y[i] = fmaxf(v, 0.f) + res[i];
}

// ---------------- final fc2: LDS-staged rows ----------------
__global__ void fc2_kernel(const float* __restrict__ in, const float* __restrict__ w,
                           const float* __restrict__ b, float* __restrict__ out,
                           int N, int OUT) {
    __shared__ float wsm[16 * 132];
    __shared__ float xs[16][129];
    int tid = threadIdx.x;
    for (int i = tid; i < OUT * H; i += 256) {
        int o = i >> 7, k = i & 127;
        wsm[o * 132 + k] = w[i];
    }
    int nb = blockIdx.x * 16;
    for (int i = tid; i < 16 * 128; i += 256) {
        int n = i >> 7, k = i & 127;
        int gn = nb + n;
        xs[n][k] = (gn < N) ? in[(size_t)gn * H + k] : 0.f;
    }
    __syncthreads();
    int o = tid & 15;
    int nn = tid >> 4;
    int n = nb + nn;
    if (n >= N || o >= OUT) return;
    const float* xr = xs[nn];
    const float* wr = wsm + o * 132;
    float acc = b[o];
#pragma unroll 8
    for (int k = 0; k < H; k += 4) {
        acc += xr[k] * wr[k] + xr[k + 1] * wr[k + 1] + xr[k + 2] * wr[k + 2] + xr[k + 3] * wr[k + 3];
    }
    out[(size_t)n * OUT + o] = acc;
}

// ---------------- launch ----------------

extern "C" void kernel_launch(void* const* d_in, const int* in_sizes, int n_in,
                              void* d_out, int out_size, void* d_ws, size_t ws_size,
                              hipStream_t stream) {
    const float* x       = (const float*)d_in[0];
    const int*   ei      = (const int*)d_in[1];
    const float* sat_w   = (const float*)d_in[2];
    const float* sat_b   = (const float*)d_in[3];
    const float* neigh_w = (const float*)d_in[4];
    const float* neigh_b = (const float*)d_in[5];
    const float* fus_w   = (const float*)d_in[6];
    const float* fus_b   = (const float*)d_in[7];
    const float* w1      = (const float*)d_in[8];
    const float* as1     = (const float*)d_in[9];
    const float* ad1     = (const float*)d_in[10];
    const float* g1      = (const float*)d_in[12];
    const float* be1     = (const float*)d_in[13];
    const float* w2      = (const float*)d_in[14];
    const float* as2     = (const float*)d_in[15];
    const float* ad2     = (const float*)d_in[16];
    const float* g2      = (const float*)d_in[18];
    const float* be2     = (const float*)d_in[19];
    const float* fc1_w   = (const float*)d_in[20];
    const float* fc1_b   = (const float*)d_in[21];
    const float* fc2_w   = (const float*)d_in[22];
    const float* fc2_b   = (const float*)d_in[23];

    int N = in_sizes[0] / 64;
    int E = in_sizes[1] / 2;
    int OUT = in_sizes[23];
    int NB = (N + SCB - 1) / SCB;

    float* ws    = (float*)d_ws;
    float* h0    = ws;                      // N*H fp32
    float* hA    = h0 + (size_t)N * H;      // N*H region (bf16 for GAT / fp32 for fc1)
    float* agg   = hA + (size_t)N * H;      // N*H fp32
    float* al_s  = agg + (size_t)N * H;     // N
    float* al_d  = al_s + N;                // N
    float* accum = al_d + N;                // 512
    int* rowptr  = (int*)(accum + 512);     // N+1
    int* cnt     = rowptr + (N + 1);        // N
    int* cursor  = cnt + N;                 // N
    int* nodeoff = cursor + N;              // N
    int* blocksum= nodeoff + N;             // NB
    int* blockoff= blocksum + NB;           // NB
    int* ssrc    = blockoff + NB;           // E
    unsigned short* hAb = (unsigned short*)hA;

    const int* srcp = ei;
    const int* dstp = ei + E;

    dim3 b256(256);
    int gGemm = (N + 63) / 64;
    int gNH = (N * H + 255) / 256;
    int gWaveN = (N + 3) / 4;
    int gOwn = 512 * 8;

    // ---- fuse ----
    fuse_kernel<<<gGemm, b256, 0, stream>>>(x, sat_w, sat_b, neigh_w, neigh_b, fus_w, fus_b, h0, N);

    // ---- CSR build (XCD-ownership; real edges only) ----
    fill_u32<<<(N + 255) / 256, b256, 0, stream>>>((unsigned*)cnt, 0u, N);
    hist8<<<gOwn, b256, 0, stream>>>(dstp, cnt, E, N);
    scan_a<<<NB, SCB, 0, stream>>>(cnt, nodeoff, blocksum, N);
    scan_b<<<1, 1024, 0, stream>>>(blocksum, blockoff, rowptr + N, NB);
    scan_c<<<NB, SCB, 0, stream>>>(nodeoff, blockoff, rowptr, cursor, accum, N);
    scatter8<<<gOwn, b256, 0, stream>>>(srcp, dstp, cursor, ssrc, E, N);

    // ================= GAT layer 1 =================
    gemm128<1, 1><<<gGemm, b256, 0, stream>>>(h0, w1, nullptr, 0, hAb, N, as1, ad1, al_s, al_d);
    gat_agg<1><<<gWaveN, b256, 0, stream>>>(rowptr, ssrc, al_s, al_d, hAb, agg, N);
    bn_stats<<<512, b256, 0, stream>>>(agg, accum, N);
    bn_apply<<<gNH, b256, 0, stream>>>(agg, accum, g1, be1, h0, N);

    // ================= GAT layer 2 =================
    gemm128<2, 1><<<gGemm, b256, 0, stream>>>(agg, w2, nullptr, 0, hAb, N, as2, ad2, al_s, al_d);
    gat_agg<2><<<gWaveN, b256, 0, stream>>>(rowptr, ssrc, al_s, al_d, hAb, h0, N);
    bn_stats<<<512, b256, 0, stream>>>(h0, accum + 256, N);
    bn_apply<<<gNH, b256, 0, stream>>>(h0, accum + 256, g2, be2, agg, N);

    // ================= head =================
    gemm128<3, 0><<<gGemm, b256, 0, stream>>>(h0, fc1_w, fc1_b, 1, hA, N, nullptr, nullptr, nullptr, nullptr);
    fc2_kernel<<<(N + 15) / 16, b256, 0, stream>>>(hA, fc2_w, fc2_b, (float*)d_out, N, OUT);
}

// Round 10
// 645.372 us; speedup vs baseline: 1.1499x; 1.1499x over previous
//
#include <hip/hip_runtime.h>

#define H 128

__device__ __forceinline__ float bf2f(unsigned short u) {
    return __uint_as_float(((unsigned)u) << 16);
}
__device__ __forceinline__ unsigned short f2bf(float f) {
    unsigned u = __float_as_uint(f);
    unsigned r = (u + 0x7fffu + ((u >> 16) & 1u)) >> 16;
    return (unsigned short)r;
}

__global__ void fill_u32(unsigned* __restrict__ p, unsigned v, int n) {
    int i = blockIdx.x * blockDim.x + threadIdx.x;
    if (i < n) p[i] = v;
}

// ---------------- fuse: 64-node tile, lane=node, wave-uniform weights ----------------
__global__ void fuse_kernel(const float* __restrict__ x,
                            const float* __restrict__ sat_w, const float* __restrict__ sat_b,
                            const float* __restrict__ neigh_w, const float* __restrict__ neigh_b,
                            const float* __restrict__ fus_w, const float* __restrict__ fus_b,
                            float* __restrict__ h0, int N) {
    __shared__ float xs[64 * 68];
    __shared__ float outs[64 * 132];
    __shared__ float reds[4][64];
    int tid = threadIdx.x;
    int base = blockIdx.x * 64;
    for (int i = tid; i < 64 * 64; i += 256) {
        int n = i >> 6, k = i & 63;
        int gn = base + n;
        xs[n * 68 + k] = (gn < N) ? x[(size_t)gn * 64 + k] : 0.f;
    }
    __syncthreads();
    int lane = tid & 63;
    int wv = __builtin_amdgcn_readfirstlane(tid >> 6);
    float xa[32], xb[32];
#pragma unroll
    for (int i = 0; i < 32; i += 4) {
        *(float4*)&xa[i] = *(const float4*)&xs[lane * 68 + i];
        *(float4*)&xb[i] = *(const float4*)&xs[lane * 68 + 32 + i];
    }
    float sat[32], nei[32];
    float part = 0.f;
#pragma unroll
    for (int f = 0; f < 32; ++f) {
        int gf = wv * 32 + f;
        const float* swr = sat_w + (size_t)gf * 32;
        const float* nwr = neigh_w + (size_t)gf * 32;
        float a = sat_b[gf], b = neigh_b[gf];
#pragma unroll
        for (int k = 0; k < 32; ++k) {
            a += xa[k] * swr[k];
            b += xb[k] * nwr[k];
        }
        a = fmaxf(a, 0.f);
        b = fmaxf(b, 0.f);
        sat[f] = a;
        nei[f] = b;
        part += a * fus_w[gf] + b * fus_w[128 + gf];
    }
    reds[wv][lane] = part;
    __syncthreads();
    float tot = reds[0][lane] + reds[1][lane] + reds[2][lane] + reds[3][lane];
    float g = 1.f / (1.f + __expf(-(tot + fus_b[0])));
#pragma unroll
    for (int f = 0; f < 32; ++f) {
        outs[lane * 132 + wv * 32 + f] = g * sat[f] + (1.f - g) * nei[f];
    }
    __syncthreads();
    for (int i = tid; i < 64 * 128; i += 256) {
        int n = i >> 7, k = i & 127;
        int gn = base + n;
        if (gn < N) h0[(size_t)gn * H + k] = outs[n * 132 + k];
    }
}

// ---------------- 128x128 GEMM: cb-outer (8 live accs), float4 LDS, fused logits ----------------
template <int TAG, int OBF16>
__global__ void gemm128(const float* __restrict__ in, const float* __restrict__ w,
                        const float* __restrict__ bias, int do_relu,
                        void* __restrict__ outv, int N,
                        const float* __restrict__ a_sp, const float* __restrict__ a_dp,
                        float* __restrict__ al_s, float* __restrict__ al_d) {
    __shared__ float xl[64 * 132]; // pad 132: float4-aligned
    __shared__ float reds[4][64];
    __shared__ float redd[4][64];
    int tid = threadIdx.x;
    int base = blockIdx.x * 64;
    for (int i = tid; i < 64 * 128; i += 256) {
        int n = i >> 7, k = i & 127;
        int gn = base + n;
        xl[n * 132 + k] = (gn < N) ? in[(size_t)gn * 128 + k] : 0.f;
    }
    __syncthreads();
    int lane = tid & 63;
    int wv = __builtin_amdgcn_readfirstlane(tid >> 6); // wave-uniform -> scalar w loads
    int xb = lane * 132;
    float accs[32];
    for (int cb = 0; cb < 4; ++cb) {
        int col0 = wv * 32 + cb * 8;
        const float* w0 = w + (size_t)col0 * 128;
        float acc[8] = {0.f, 0.f, 0.f, 0.f, 0.f, 0.f, 0.f, 0.f};
        for (int kc = 0; kc < 128; kc += 16) {
            float xv[16];
#pragma unroll
            for (int i = 0; i < 16; i += 4) *(float4*)&xv[i] = *(const float4*)&xl[xb + kc + i];
#pragma unroll
            for (int j = 0; j < 8; ++j) {
                const float* wr = w0 + (size_t)j * 128 + kc; // wave-uniform contiguous 16
#pragma unroll
                for (int i = 0; i < 16; ++i) acc[j] += xv[i] * wr[i];
            }
        }
#pragma unroll
        for (int j = 0; j < 8; ++j) {
            float v = acc[j] + (bias ? bias[col0 + j] : 0.f);
            if (do_relu) v = fmaxf(v, 0.f);
            accs[cb * 8 + j] = v;
        }
    }
    __syncthreads();
#pragma unroll
    for (int j = 0; j < 32; j += 4) *(float4*)&xl[xb + wv * 32 + j] = *(float4*)&accs[j];
    __syncthreads();
    for (int i = tid; i < 64 * 128; i += 256) {
        int n = i >> 7, k = i & 127;
        int gn = base + n;
        if (gn < N) {
            if (OBF16) ((unsigned short*)outv)[(size_t)gn * H + k] = f2bf(xl[n * 132 + k]);
            else       ((float*)outv)[(size_t)gn * H + k] = xl[n * 132 + k];
        }
    }
    if (a_sp) {
        int node = tid & 63;
        int part = tid >> 6;
        float ps = 0.f, pd = 0.f;
        int kb = part * 32;
        const float* xr = xl + node * 132 + kb;
#pragma unroll
        for (int k = 0; k < 32; ++k) {
            float v = xr[k];
            ps += v * a_sp[kb + k];
            pd += v * a_dp[kb + k];
        }
        reds[part][node] = ps;
        redd[part][node] = pd;
        __syncthreads();
        if (tid < 64) {
            int gn = base + tid;
            if (gn < N) {
                al_s[gn] = reds[0][tid] + reds[1][tid] + reds[2][tid] + reds[3][tid];
                al_d[gn] = redd[0][tid] + redd[1][tid] + redd[2][tid] + redd[3][tid];
            }
        }
    }
}

// ---------------- CSR build with XCD-ownership ----------------
#define SCB 256
__global__ void hist8(const int* __restrict__ dst, int* __restrict__ cnt, int E, int N) {
    int g = blockIdx.x & 7;
    int chunk = blockIdx.x >> 3;
    int nch = gridDim.x >> 3;
    int NR = (N + 7) >> 3;
    int lo = g * NR;
    int hi = min(lo + NR, N);
    for (int e = chunk * SCB + threadIdx.x; e < E; e += nch * SCB) {
        int d = dst[e];
        if (d >= lo && d < hi) atomicAdd(cnt + d, 1);
    }
}

__global__ void scan_a(const int* __restrict__ cnt, int* __restrict__ nodeoff,
                       int* __restrict__ blocksum, int N) {
    int i = blockIdx.x * SCB + threadIdx.x;
    int tot = (i < N) ? cnt[i] : 0;
    __shared__ int tmp[SCB];
    tmp[threadIdx.x] = tot;
    __syncthreads();
    for (int off = 1; off < SCB; off <<= 1) {
        int t = (threadIdx.x >= off) ? tmp[threadIdx.x - off] : 0;
        __syncthreads();
        tmp[threadIdx.x] += t;
        __syncthreads();
    }
    if (i < N) nodeoff[i] = tmp[threadIdx.x] - tot;
    if (threadIdx.x == SCB - 1) blocksum[blockIdx.x] = tmp[SCB - 1];
}

__global__ void scan_b(const int* __restrict__ blocksum, int* __restrict__ blockoff,
                       int* __restrict__ rowptrN, int NB) {
    __shared__ int tmp[1024];
    int t = threadIdx.x;
    int v = (t < NB) ? blocksum[t] : 0;
    tmp[t] = v;
    __syncthreads();
    for (int off = 1; off < 1024; off <<= 1) {
        int u = (t >= off) ? tmp[t - off] : 0;
        __syncthreads();
        tmp[t] += u;
        __syncthreads();
    }
    if (t < NB) blockoff[t] = tmp[t] - v;
    if (t == 1023) *rowptrN = tmp[1023];
}

__global__ void scan_c(const int* __restrict__ nodeoff, const int* __restrict__ blockoff,
                       int* __restrict__ rowptr, int* __restrict__ cursor,
                       float* __restrict__ accum2, int N) {
    if (blockIdx.x < 2) {
        accum2[blockIdx.x * 256 + threadIdx.x] = 0.f;
    }
    int i = blockIdx.x * SCB + threadIdx.x;
    if (i >= N) return;
    int run = blockoff[blockIdx.x] + nodeoff[i];
    rowptr[i] = run;
    cursor[i] = run;
}

__global__ void scatter8(const int* __restrict__ src, const int* __restrict__ dst,
                         int* __restrict__ cursor, int* __restrict__ ssrc, int E, int N) {
    int g = blockIdx.x & 7;
    int chunk = blockIdx.x >> 3;
    int nch = gridDim.x >> 3;
    int NR = (N + 7) >> 3;
    int lo = g * NR;
    int hi = min(lo + NR, N);
    for (int e = chunk * SCB + threadIdx.x; e < E; e += nch * SCB) {
        int d = dst[e];
        if (d >= lo && d < hi) {
            int pos = atomicAdd(cursor + d, 1);
            ssrc[pos] = src[e];
        }
    }
}

// ---------------- GAT aggregation: one wave per dst node, bf16 h ----------------
#define PF 8
template <int TAG>
__global__ void gat_agg(const int* __restrict__ rowptr, const int* __restrict__ ssrc,
                        const float* __restrict__ al_s, const float* __restrict__ al_d,
                        const unsigned short* __restrict__ hb, float* __restrict__ out, int N) {
    __shared__ int s_sv[4][64];
    __shared__ float s_ev[4][64];
    int wiw = threadIdx.x >> 6;
    int w = (blockIdx.x * blockDim.x + threadIdx.x) >> 6;
    int lane = threadIdx.x & 63;
    if (w >= N) return;
    int beg = rowptr[w], end = rowptr[w + 1];
    float ald = al_d[w];
    float a_self = al_s[w] + ald;
    a_self = (a_self > 0.f) ? a_self : 0.2f * a_self;
    float m = a_self;
    for (int e = beg + lane; e < end; e += 64) {
        float a = al_s[ssrc[e]] + ald;
        a = (a > 0.f) ? a : 0.2f * a;
        m = fmaxf(m, a);
    }
    for (int off = 32; off; off >>= 1) m = fmaxf(m, __shfl_xor(m, off));
    float ss = 0.f, acc0 = 0.f, acc1 = 0.f;
    for (int base = beg; base < end; base += 64) {
        int nch = min(64, end - base);
        int sv = 0;
        float ev = 0.f;
        if (lane < nch) {
            sv = ssrc[base + lane];
            float a = al_s[sv] + ald;
            a = (a > 0.f) ? a : 0.2f * a;
            ev = __expf(a - m);
        }
        ss += ev;
        s_sv[wiw][lane] = sv;
        s_ev[wiw][lane] = ev;
        for (int j0 = 0; j0 < nch; j0 += PF) {
            int np = min(PF, nch - j0);
            ushort2 hv[PF];
#pragma unroll
            for (int jj = 0; jj < PF; ++jj) {
                if (jj < np) {
                    int svj = s_sv[wiw][j0 + jj];
                    hv[jj] = ((const ushort2*)(hb + (size_t)svj * H))[lane];
                }
            }
#pragma unroll
            for (int jj = 0; jj < PF; ++jj) {
                if (jj < np) {
                    float evj = s_ev[wiw][j0 + jj];
                    acc0 += evj * bf2f(hv[jj].x);
                    acc1 += evj * bf2f(hv[jj].y);
                }
            }
        }
    }
    for (int off = 32; off; off >>= 1) ss += __shfl_xor(ss, off);
    float ev_self = __expf(a_self - m);
    ss += ev_self;
    ushort2 hs = ((const ushort2*)(hb + (size_t)w * H))[lane];
    acc0 += ev_self * bf2f(hs.x);
    acc1 += ev_self * bf2f(hs.y);
    float inv = 1.f / (ss + 1e-16f);
    ((float2*)(out + (size_t)w * H))[lane] = make_float2(acc0 * inv, acc1 * inv);
}

// ---------------- BN stats ----------------
__global__ void bn_stats(const float* __restrict__ y, float* __restrict__ accum, int N) {
    int f = threadIdx.x & 127;
    int half = threadIdx.x >> 7;
    float sum = 0.f, sumsq = 0.f;
    for (int n = blockIdx.x * 2 + half; n < N; n += gridDim.x * 2) {
        float v = y[(size_t)n * H + f];
        sum += v;
        sumsq += v * v;
    }
    __shared__ float ls[2][128], ls2[2][128];
    ls[half][f] = sum;
    ls2[half][f] = sumsq;
    __syncthreads();
    if (half == 0) {
        atomicAdd(accum + f, ls[0][f] + ls[1][f]);
        atomicAdd(accum + 128 + f, ls2[0][f] + ls2[1][f]);
    }
}

// ---------------- BN apply + relu + residual ----------------
__global__ void bn_apply(float* __restrict__ y, const float* __restrict__ accum,
                         const float* __restrict__ g, const float* __restrict__ be,
                         const float* __restrict__ res, int N) {
    int i = blockIdx.x * blockDim.x + threadIdx.x;
    if (i >= N * H) return;
    int f = i & 127;
    float Ninv = 1.f / (float)N;
    float mu = accum[f] * Ninv;
    float var = accum[128 + f] * Ninv - mu * mu;
    float v = (y[i] - mu) * rsqrtf(var + 1e-5f) * g[f] + be[f];
    y[i] = fmaxf(v, 0.f) + res[i];
}

// ---------------- final fc2: LDS-staged rows ----------------
__global__ void fc2_kernel(const float* __restrict__ in, const float* __restrict__ w,
                           const float* __restrict__ b, float* __restrict__ out,
                           int N, int OUT) {
    __shared__ float wsm[16 * 132];
    __shared__ float xs[16][129];
    int tid = threadIdx.x;
    for (int i = tid; i < OUT * H; i += 256) {
        int o = i >> 7, k = i & 127;
        wsm[o * 132 + k] = w[i];
    }
    int nb = blockIdx.x * 16;
    for (int i = tid; i < 16 * 128; i += 256) {
        int n = i >> 7, k = i & 127;
        int gn = nb + n;
        xs[n][k] = (gn < N) ? in[(size_t)gn * H + k] : 0.f;
    }
    __syncthreads();
    int o = tid & 15;
    int nn = tid >> 4;
    int n = nb + nn;
    if (n >= N || o >= OUT) return;
    const float* xr = xs[nn];
    const float* wr = wsm + o * 132;
    float acc = b[o];
#pragma unroll 8
    for (int k = 0; k < H; k += 4) {
        acc += xr[k] * wr[k] + xr[k + 1] * wr[k + 1] + xr[k + 2] * wr[k + 2] + xr[k + 3] * wr[k + 3];
    }
    out[(size_t)n * OUT + o] = acc;
}

// ---------------- launch ----------------

extern "C" void kernel_launch(void* const* d_in, const int* in_sizes, int n_in,
                              void* d_out, int out_size, void* d_ws, size_t ws_size,
                              hipStream_t stream) {
    const float* x       = (const float*)d_in[0];
    const int*   ei      = (const int*)d_in[1];
    const float* sat_w   = (const float*)d_in[2];
    const float* sat_b   = (const float*)d_in[3];
    const float* neigh_w = (const float*)d_in[4];
    const float* neigh_b = (const float*)d_in[5];
    const float* fus_w   = (const float*)d_in[6];
    const float* fus_b   = (const float*)d_in[7];
    const float* w1      = (const float*)d_in[8];
    const float* as1     = (const float*)d_in[9];
    const float* ad1     = (const float*)d_in[10];
    const float* g1      = (const float*)d_in[12];
    const float* be1     = (const float*)d_in[13];
    const float* w2      = (const float*)d_in[14];
    const float* as2     = (const float*)d_in[15];
    const float* ad2     = (const float*)d_in[16];
    const float* g2      = (const float*)d_in[18];
    const float* be2     = (const float*)d_in[19];
    const float* fc1_w   = (const float*)d_in[20];
    const float* fc1_b   = (const float*)d_in[21];
    const float* fc2_w   = (const float*)d_in[22];
    const float* fc2_b   = (const float*)d_in[23];

    int N = in_sizes[0] / 64;
    int E = in_sizes[1] / 2;
    int OUT = in_sizes[23];
    int NB = (N + SCB - 1) / SCB;

    float* ws    = (float*)d_ws;
    float* h0    = ws;                      // N*H fp32
    float* hA    = h0 + (size_t)N * H;      // N*H region (bf16 for GAT / fp32 for fc1)
    float* agg   = hA + (size_t)N * H;      // N*H fp32
    float* al_s  = agg + (size_t)N * H;     // N
    float* al_d  = al_s + N;                // N
    float* accum = al_d + N;                // 512
    int* rowptr  = (int*)(accum + 512);     // N+1
    int* cnt     = rowptr + (N + 1);        // N
    int* cursor  = cnt + N;                 // N
    int* nodeoff = cursor + N;              // N
    int* blocksum= nodeoff + N;             // NB
    int* blockoff= blocksum + NB;           // NB
    int* ssrc    = blockoff + NB;           // E
    unsigned short* hAb = (unsigned short*)hA;

    const int* srcp = ei;
    const int* dstp = ei + E;

    dim3 b256(256);
    int gGemm = (N + 63) / 64;
    int gNH = (N * H + 255) / 256;
    int gWaveN = (N + 3) / 4;
    int gOwn = 512 * 8;

    // ---- fuse ----
    fuse_kernel<<<gGemm, b256, 0, stream>>>(x, sat_w, sat_b, neigh_w, neigh_b, fus_w, fus_b, h0, N);

    // ---- CSR build (XCD-ownership; real edges only) ----
    fill_u32<<<(N + 255) / 256, b256, 0, stream>>>((unsigned*)cnt, 0u, N);
    hist8<<<gOwn, b256, 0, stream>>>(dstp, cnt, E, N);
    scan_a<<<NB, SCB, 0, stream>>>(cnt, nodeoff, blocksum, N);
    scan_b<<<1, 1024, 0, stream>>>(blocksum, blockoff, rowptr + N, NB);
    scan_c<<<NB, SCB, 0, stream>>>(nodeoff, blockoff, rowptr, cursor, accum, N);
    scatter8<<<gOwn, b256, 0, stream>>>(srcp, dstp, cursor, ssrc, E, N);

    // ================= GAT layer 1 =================
    gemm128<1, 1><<<gGemm, b256, 0, stream>>>(h0, w1, nullptr, 0, hAb, N, as1, ad1, al_s, al_d);
    gat_agg<1><<<gWaveN, b256, 0, stream>>>(rowptr, ssrc, al_s, al_d, hAb, agg, N);
    bn_stats<<<512, b256, 0, stream>>>(agg, accum, N);
    bn_apply<<<gNH, b256, 0, stream>>>(agg, accum, g1, be1, h0, N);

    // ================= GAT layer 2 =================
    gemm128<2, 1><<<gGemm, b256, 0, stream>>>(agg, w2, nullptr, 0, hAb, N, as2, ad2, al_s, al_d);
    gat_agg<2><<<gWaveN, b256, 0, stream>>>(rowptr, ssrc, al_s, al_d, hAb, h0, N);
    bn_stats<<<512, b256, 0, stream>>>(h0, accum + 256, N);
    bn_apply<<<gNH, b256, 0, stream>>>(h0, accum + 256, g2, be2, agg, N);

    // ================= head =================
    gemm128<3, 0><<<gGemm, b256, 0, stream>>>(h0, fc1_w, fc1_b, 1, hA, N, nullptr, nullptr, nullptr, nullptr);
    fc2_kernel<<<(N + 15) / 16, b256, 0, stream>>>(hA, fc2_w, fc2_b, (float*)d_out, N, OUT);
}

// Round 11
// 518.633 us; speedup vs baseline: 1.4309x; 1.2444x over previous
//
#include <hip/hip_runtime.h>

#define H 128

typedef __attribute__((ext_vector_type(8))) short bf16x8;
typedef __attribute__((ext_vector_type(4))) float f32x4;

__device__ __forceinline__ float bf2f(unsigned short u) {
    return __uint_as_float(((unsigned)u) << 16);
}
__device__ __forceinline__ unsigned short f2bf(float f) {
    unsigned u = __float_as_uint(f);
    unsigned r = (u + 0x7fffu + ((u >> 16) & 1u)) >> 16;
    return (unsigned short)r;
}
__device__ __forceinline__ unsigned pack2bf(float a, float b) {
    return (unsigned)f2bf(a) | ((unsigned)f2bf(b) << 16);
}

__global__ void fill_u32(unsigned* __restrict__ p, unsigned v, int n) {
    int i = blockIdx.x * blockDim.x + threadIdx.x;
    if (i < n) p[i] = v;
}

// ---------------- fuse: 64-node tile, lane=node, wave-uniform weights ----------------
__global__ void fuse_kernel(const float* __restrict__ x,
                            const float* __restrict__ sat_w, const float* __restrict__ sat_b,
                            const float* __restrict__ neigh_w, const float* __restrict__ neigh_b,
                            const float* __restrict__ fus_w, const float* __restrict__ fus_b,
                            float* __restrict__ h0, int N) {
    __shared__ float xs[64 * 68];
    __shared__ float outs[64 * 132];
    __shared__ float reds[4][64];
    int tid = threadIdx.x;
    int base = blockIdx.x * 64;
    for (int i = tid; i < 64 * 64; i += 256) {
        int n = i >> 6, k = i & 63;
        int gn = base + n;
        xs[n * 68 + k] = (gn < N) ? x[(size_t)gn * 64 + k] : 0.f;
    }
    __syncthreads();
    int lane = tid & 63;
    int wv = __builtin_amdgcn_readfirstlane(tid >> 6);
    float xa[32], xb[32];
#pragma unroll
    for (int i = 0; i < 32; i += 4) {
        *(float4*)&xa[i] = *(const float4*)&xs[lane * 68 + i];
        *(float4*)&xb[i] = *(const float4*)&xs[lane * 68 + 32 + i];
    }
    float sat[32], nei[32];
    float part = 0.f;
#pragma unroll
    for (int f = 0; f < 32; ++f) {
        int gf = wv * 32 + f;
        const float* swr = sat_w + (size_t)gf * 32;
        const float* nwr = neigh_w + (size_t)gf * 32;
        float a = sat_b[gf], b = neigh_b[gf];
#pragma unroll
        for (int k = 0; k < 32; ++k) {
            a += xa[k] * swr[k];
            b += xb[k] * nwr[k];
        }
        a = fmaxf(a, 0.f);
        b = fmaxf(b, 0.f);
        sat[f] = a;
        nei[f] = b;
        part += a * fus_w[gf] + b * fus_w[128 + gf];
    }
    reds[wv][lane] = part;
    __syncthreads();
    float tot = reds[0][lane] + reds[1][lane] + reds[2][lane] + reds[3][lane];
    float g = 1.f / (1.f + __expf(-(tot + fus_b[0])));
#pragma unroll
    for (int f = 0; f < 32; ++f) {
        outs[lane * 132 + wv * 32 + f] = g * sat[f] + (1.f - g) * nei[f];
    }
    __syncthreads();
    for (int i = tid; i < 64 * 128; i += 256) {
        int n = i >> 7, k = i & 127;
        int gn = base + n;
        if (gn < N) h0[(size_t)gn * H + k] = outs[n * 132 + k];
    }
}

// ---------------- MFMA bf16 GEMM: 64 nodes x 128 cols per block ----------------
// in fp32 [N,128]; w fp32 [128 cols][128 k]; out bf16 [N,128]; optional fused logits.
template <int TAG>
__global__ void gemm128m(const float* __restrict__ in, const float* __restrict__ w,
                         const float* __restrict__ bias, int do_relu,
                         unsigned short* __restrict__ outb, int N,
                         const float* __restrict__ a_sp, const float* __restrict__ a_dp,
                         float* __restrict__ al_s, float* __restrict__ al_d) {
    __shared__ unsigned a_lds[64 * 68];   // [node][k-pair], pad 68 u32 (16B-aligned rows)
    __shared__ unsigned w_lds[128 * 68];  // [col][k-pair]
    __shared__ float reds[4][64];
    __shared__ float redd[4][64];
    int tid = threadIdx.x;
    int base = blockIdx.x * 64;
    // stage A (fp32 -> bf16 pairs)
    for (int i = tid; i < 64 * 64; i += 256) {
        int n = i >> 6, kp = i & 63;
        int gn = base + n;
        float2 v = (gn < N) ? *(const float2*)(in + (size_t)gn * 128 + kp * 2)
                            : make_float2(0.f, 0.f);
        a_lds[n * 68 + kp] = pack2bf(v.x, v.y);
    }
    // stage W (fp32 -> bf16 pairs)
    for (int i = tid; i < 128 * 64; i += 256) {
        int c = i >> 6, kp = i & 63;
        float2 v = *(const float2*)(w + (size_t)c * 128 + kp * 2);
        w_lds[c * 68 + kp] = pack2bf(v.x, v.y);
    }
    __syncthreads();
    int lane = tid & 63;
    int wv = tid >> 6;       // wave: cols [wv*32, wv*32+32)
    int lr = lane & 15;      // row (A) / col (B) within 16-tile
    int lk = lane >> 4;      // k-subgroup: k = chunk*32 + lk*8 + j
    f32x4 acc[4][2];
#pragma unroll
    for (int r = 0; r < 4; ++r)
#pragma unroll
        for (int t = 0; t < 2; ++t) acc[r][t] = (f32x4){0.f, 0.f, 0.f, 0.f};
    for (int c = 0; c < 4; ++c) {
        bf16x8 af[4], bfr[2];
#pragma unroll
        for (int r = 0; r < 4; ++r)
            af[r] = *(const bf16x8*)&a_lds[(r * 16 + lr) * 68 + c * 16 + lk * 4];
#pragma unroll
        for (int t = 0; t < 2; ++t)
            bfr[t] = *(const bf16x8*)&w_lds[(wv * 32 + t * 16 + lr) * 68 + c * 16 + lk * 4];
#pragma unroll
        for (int r = 0; r < 4; ++r)
#pragma unroll
            for (int t = 0; t < 2; ++t)
                acc[r][t] = __builtin_amdgcn_mfma_f32_16x16x32_bf16(af[r], bfr[t], acc[r][t], 0, 0, 0);
    }
    // bias + relu on fragments, then stage C as bf16 into a_lds
    __syncthreads();
    unsigned short* cst = (unsigned short*)a_lds; // [64][136]
#pragma unroll
    for (int t = 0; t < 2; ++t) {
        int col = wv * 32 + t * 16 + lr;
        float bv = bias ? bias[col] : 0.f;
#pragma unroll
        for (int r = 0; r < 4; ++r) {
#pragma unroll
            for (int j = 0; j < 4; ++j) {
                float v = acc[r][t][j] + bv;
                if (do_relu) v = fmaxf(v, 0.f);
                cst[(r * 16 + lk * 4 + j) * 136 + col] = f2bf(v);
            }
        }
    }
    __syncthreads();
    // coalesced global write (u32 = 2 bf16)
    for (int i = tid; i < 64 * 64; i += 256) {
        int n = i >> 6, kp = i & 63;
        int gn = base + n;
        if (gn < N) ((unsigned*)outb)[(size_t)gn * 64 + kp] = a_lds[n * 68 + kp];
    }
    // fused attention logits from C tile
    if (a_sp) {
        int node = tid & 63;
        int part = tid >> 6;
        float ps = 0.f, pd = 0.f;
        int kb = part * 32;
        const unsigned short* xr = cst + node * 136 + kb;
#pragma unroll
        for (int k = 0; k < 32; ++k) {
            float v = bf2f(xr[k]);
            ps += v * a_sp[kb + k];
            pd += v * a_dp[kb + k];
        }
        reds[part][node] = ps;
        redd[part][node] = pd;
        __syncthreads();
        if (tid < 64) {
            int gn = base + tid;
            if (gn < N) {
                al_s[gn] = reds[0][tid] + reds[1][tid] + reds[2][tid] + reds[3][tid];
                al_d[gn] = redd[0][tid] + redd[1][tid] + redd[2][tid] + redd[3][tid];
            }
        }
    }
}

// ---------------- CSR build with XCD-ownership ----------------
#define SCB 256
__global__ void hist8(const int* __restrict__ dst, int* __restrict__ cnt, int E, int N) {
    int g = blockIdx.x & 7;
    int chunk = blockIdx.x >> 3;
    int nch = gridDim.x >> 3;
    int NR = (N + 7) >> 3;
    int lo = g * NR;
    int hi = min(lo + NR, N);
    for (int e = chunk * SCB + threadIdx.x; e < E; e += nch * SCB) {
        int d = dst[e];
        if (d >= lo && d < hi) atomicAdd(cnt + d, 1);
    }
}

__global__ void scan_a(const int* __restrict__ cnt, int* __restrict__ nodeoff,
                       int* __restrict__ blocksum, int N) {
    int i = blockIdx.x * SCB + threadIdx.x;
    int tot = (i < N) ? cnt[i] : 0;
    __shared__ int tmp[SCB];
    tmp[threadIdx.x] = tot;
    __syncthreads();
    for (int off = 1; off < SCB; off <<= 1) {
        int t = (threadIdx.x >= off) ? tmp[threadIdx.x - off] : 0;
        __syncthreads();
        tmp[threadIdx.x] += t;
        __syncthreads();
    }
    if (i < N) nodeoff[i] = tmp[threadIdx.x] - tot;
    if (threadIdx.x == SCB - 1) blocksum[blockIdx.x] = tmp[SCB - 1];
}

__global__ void scan_b(const int* __restrict__ blocksum, int* __restrict__ blockoff,
                       int* __restrict__ rowptrN, int NB) {
    __shared__ int tmp[1024];
    int t = threadIdx.x;
    int v = (t < NB) ? blocksum[t] : 0;
    tmp[t] = v;
    __syncthreads();
    for (int off = 1; off < 1024; off <<= 1) {
        int u = (t >= off) ? tmp[t - off] : 0;
        __syncthreads();
        tmp[t] += u;
        __syncthreads();
    }
    if (t < NB) blockoff[t] = tmp[t] - v;
    if (t == 1023) *rowptrN = tmp[1023];
}

__global__ void scan_c(const int* __restrict__ nodeoff, const int* __restrict__ blockoff,
                       int* __restrict__ rowptr, int* __restrict__ cursor,
                       float* __restrict__ accum2, int N) {
    if (blockIdx.x < 2) {
        accum2[blockIdx.x * 256 + threadIdx.x] = 0.f;
    }
    int i = blockIdx.x * SCB + threadIdx.x;
    if (i >= N) return;
    int run = blockoff[blockIdx.x] + nodeoff[i];
    rowptr[i] = run;
    cursor[i] = run;
}

__global__ void scatter8(const int* __restrict__ src, const int* __restrict__ dst,
                         int* __restrict__ cursor, int* __restrict__ ssrc, int E, int N) {
    int g = blockIdx.x & 7;
    int chunk = blockIdx.x >> 3;
    int nch = gridDim.x >> 3;
    int NR = (N + 7) >> 3;
    int lo = g * NR;
    int hi = min(lo + NR, N);
    for (int e = chunk * SCB + threadIdx.x; e < E; e += nch * SCB) {
        int d = dst[e];
        if (d >= lo && d < hi) {
            int pos = atomicAdd(cursor + d, 1);
            ssrc[pos] = src[e];
        }
    }
}

// ---------------- GAT aggregation: one wave per dst node, bf16 h ----------------
#define PF 8
template <int TAG>
__global__ void gat_agg(const int* __restrict__ rowptr, const int* __restrict__ ssrc,
                        const float* __restrict__ al_s, const float* __restrict__ al_d,
                        const unsigned short* __restrict__ hb, float* __restrict__ out, int N) {
    __shared__ int s_sv[4][64];
    __shared__ float s_ev[4][64];
    int wiw = threadIdx.x >> 6;
    int w = (blockIdx.x * blockDim.x + threadIdx.x) >> 6;
    int lane = threadIdx.x & 63;
    if (w >= N) return;
    int beg = rowptr[w], end = rowptr[w + 1];
    float ald = al_d[w];
    float a_self = al_s[w] + ald;
    a_self = (a_self > 0.f) ? a_self : 0.2f * a_self;
    float m = a_self;
    for (int e = beg + lane; e < end; e += 64) {
        float a = al_s[ssrc[e]] + ald;
        a = (a > 0.f) ? a : 0.2f * a;
        m = fmaxf(m, a);
    }
    for (int off = 32; off; off >>= 1) m = fmaxf(m, __shfl_xor(m, off));
    float ss = 0.f, acc0 = 0.f, acc1 = 0.f;
    for (int base = beg; base < end; base += 64) {
        int nch = min(64, end - base);
        int sv = 0;
        float ev = 0.f;
        if (lane < nch) {
            sv = ssrc[base + lane];
            float a = al_s[sv] + ald;
            a = (a > 0.f) ? a : 0.2f * a;
            ev = __expf(a - m);
        }
        ss += ev;
        s_sv[wiw][lane] = sv;
        s_ev[wiw][lane] = ev;
        for (int j0 = 0; j0 < nch; j0 += PF) {
            int np = min(PF, nch - j0);
            ushort2 hv[PF];
#pragma unroll
            for (int jj = 0; jj < PF; ++jj) {
                if (jj < np) {
                    int svj = s_sv[wiw][j0 + jj];
                    hv[jj] = ((const ushort2*)(hb + (size_t)svj * H))[lane];
                }
            }
#pragma unroll
            for (int jj = 0; jj < PF; ++jj) {
                if (jj < np) {
                    float evj = s_ev[wiw][j0 + jj];
                    acc0 += evj * bf2f(hv[jj].x);
                    acc1 += evj * bf2f(hv[jj].y);
                }
            }
        }
    }
    for (int off = 32; off; off >>= 1) ss += __shfl_xor(ss, off);
    float ev_self = __expf(a_self - m);
    ss += ev_self;
    ushort2 hs = ((const ushort2*)(hb + (size_t)w * H))[lane];
    acc0 += ev_self * bf2f(hs.x);
    acc1 += ev_self * bf2f(hs.y);
    float inv = 1.f / (ss + 1e-16f);
    ((float2*)(out + (size_t)w * H))[lane] = make_float2(acc0 * inv, acc1 * inv);
}

// ---------------- BN stats ----------------
__global__ void bn_stats(const float* __restrict__ y, float* __restrict__ accum, int N) {
    int f = threadIdx.x & 127;
    int half = threadIdx.x >> 7;
    float sum = 0.f, sumsq = 0.f;
    for (int n = blockIdx.x * 2 + half; n < N; n += gridDim.x * 2) {
        float v = y[(size_t)n * H + f];
        sum += v;
        sumsq += v * v;
    }
    __shared__ float ls[2][128], ls2[2][128];
    ls[half][f] = sum;
    ls2[half][f] = sumsq;
    __syncthreads();
    if (half == 0) {
        atomicAdd(accum + f, ls[0][f] + ls[1][f]);
        atomicAdd(accum + 128 + f, ls2[0][f] + ls2[1][f]);
    }
}

// ---------------- BN apply + relu + residual ----------------
__global__ void bn_apply(float* __restrict__ y, const float* __restrict__ accum,
                         const float* __restrict__ g, const float* __restrict__ be,
                         const float* __restrict__ res, int N) {
    int i = blockIdx.x * blockDim.x + threadIdx.x;
    if (i >= N * H) return;
    int f = i & 127;
    float Ninv = 1.f / (float)N;
    float mu = accum[f] * Ninv;
    float var = accum[128 + f] * Ninv - mu * mu;
    float v = (y[i] - mu) * rsqrtf(var + 1e-5f) * g[f] + be[f];
    y[i] = fmaxf(v, 0.f) + res[i];
}

// ---------------- final fc2: bf16 input rows staged in LDS ----------------
__global__ void fc2_kernel(const unsigned short* __restrict__ in, const float* __restrict__ w,
                           const float* __restrict__ b, float* __restrict__ out,
                           int N, int OUT) {
    __shared__ float wsm[16 * 132];
    __shared__ float xs[16][129];
    int tid = threadIdx.x;
    for (int i = tid; i < OUT * H; i += 256) {
        int o = i >> 7, k = i & 127;
        wsm[o * 132 + k] = w[i];
    }
    int nb = blockIdx.x * 16;
    for (int i = tid; i < 16 * 128; i += 256) {
        int n = i >> 7, k = i & 127;
        int gn = nb + n;
        xs[n][k] = (gn < N) ? bf2f(in[(size_t)gn * H + k]) : 0.f;
    }
    __syncthreads();
    int o = tid & 15;
    int nn = tid >> 4;
    int n = nb + nn;
    if (n >= N || o >= OUT) return;
    const float* xr = xs[nn];
    const float* wr = wsm + o * 132;
    float acc = b[o];
#pragma unroll 8
    for (int k = 0; k < H; k += 4) {
        acc += xr[k] * wr[k] + xr[k + 1] * wr[k + 1] + xr[k + 2] * wr[k + 2] + xr[k + 3] * wr[k + 3];
    }
    out[(size_t)n * OUT + o] = acc;
}

// ---------------- launch ----------------

extern "C" void kernel_launch(void* const* d_in, const int* in_sizes, int n_in,
                              void* d_out, int out_size, void* d_ws, size_t ws_size,
                              hipStream_t stream) {
    const float* x       = (const float*)d_in[0];
    const int*   ei      = (const int*)d_in[1];
    const float* sat_w   = (const float*)d_in[2];
    const float* sat_b   = (const float*)d_in[3];
    const float* neigh_w = (const float*)d_in[4];
    const float* neigh_b = (const float*)d_in[5];
    const float* fus_w   = (const float*)d_in[6];
    const float* fus_b   = (const float*)d_in[7];
    const float* w1      = (const float*)d_in[8];
    const float* as1     = (const float*)d_in[9];
    const float* ad1     = (const float*)d_in[10];
    const float* g1      = (const float*)d_in[12];
    const float* be1     = (const float*)d_in[13];
    const float* w2      = (const float*)d_in[14];
    const float* as2     = (const float*)d_in[15];
    const float* ad2     = (const float*)d_in[16];
    const float* g2      = (const float*)d_in[18];
    const float* be2     = (const float*)d_in[19];
    const float* fc1_w   = (const float*)d_in[20];
    const float* fc1_b   = (const float*)d_in[21];
    const float* fc2_w   = (const float*)d_in[22];
    const float* fc2_b   = (const float*)d_in[23];

    int N = in_sizes[0] / 64;
    int E = in_sizes[1] / 2;
    int OUT = in_sizes[23];
    int NB = (N + SCB - 1) / SCB;

    float* ws    = (float*)d_ws;
    float* h0    = ws;                      // N*H fp32
    float* hA    = h0 + (size_t)N * H;      // N*H region (bf16 outputs of gemms)
    float* agg   = hA + (size_t)N * H;      // N*H fp32
    float* al_s  = agg + (size_t)N * H;     // N
    float* al_d  = al_s + N;                // N
    float* accum = al_d + N;                // 512
    int* rowptr  = (int*)(accum + 512);     // N+1
    int* cnt     = rowptr + (N + 1);        // N
    int* cursor  = cnt + N;                 // N
    int* nodeoff = cursor + N;              // N
    int* blocksum= nodeoff + N;             // NB
    int* blockoff= blocksum + NB;           // NB
    int* ssrc    = blockoff + NB;           // E
    unsigned short* hAb = (unsigned short*)hA;

    const int* srcp = ei;
    const int* dstp = ei + E;

    dim3 b256(256);
    int gGemm = (N + 63) / 64;
    int gNH = (N * H + 255) / 256;
    int gWaveN = (N + 3) / 4;
    int gOwn = 512 * 8;

    // ---- fuse ----
    fuse_kernel<<<gGemm, b256, 0, stream>>>(x, sat_w, sat_b, neigh_w, neigh_b, fus_w, fus_b, h0, N);

    // ---- CSR build (XCD-ownership; real edges only) ----
    fill_u32<<<(N + 255) / 256, b256, 0, stream>>>((unsigned*)cnt, 0u, N);
    hist8<<<gOwn, b256, 0, stream>>>(dstp, cnt, E, N);
    scan_a<<<NB, SCB, 0, stream>>>(cnt, nodeoff, blocksum, N);
    scan_b<<<1, 1024, 0, stream>>>(blocksum, blockoff, rowptr + N, NB);
    scan_c<<<NB, SCB, 0, stream>>>(nodeoff, blockoff, rowptr, cursor, accum, N);
    scatter8<<<gOwn, b256, 0, stream>>>(srcp, dstp, cursor, ssrc, E, N);

    // ================= GAT layer 1 =================
    gemm128m<1><<<gGemm, b256, 0, stream>>>(h0, w1, nullptr, 0, hAb, N, as1, ad1, al_s, al_d);
    gat_agg<1><<<gWaveN, b256, 0, stream>>>(rowptr, ssrc, al_s, al_d, hAb, agg, N);
    bn_stats<<<512, b256, 0, stream>>>(agg, accum, N);
    bn_apply<<<gNH, b256, 0, stream>>>(agg, accum, g1, be1, h0, N);

    // ================= GAT layer 2 =================
    gemm128m<2><<<gGemm, b256, 0, stream>>>(agg, w2, nullptr, 0, hAb, N, as2, ad2, al_s, al_d);
    gat_agg<2><<<gWaveN, b256, 0, stream>>>(rowptr, ssrc, al_s, al_d, hAb, h0, N);
    bn_stats<<<512, b256, 0, stream>>>(h0, accum + 256, N);
    bn_apply<<<gNH, b256, 0, stream>>>(h0, accum + 256, g2, be2, agg, N);

    // ================= head =================
    gemm128m<3><<<gGemm, b256, 0, stream>>>(h0, fc1_w, fc1_b, 1, hAb, N, nullptr, nullptr, nullptr, nullptr);
    fc2_kernel<<<(N + 15) / 16, b256, 0, stream>>>(hAb, fc2_w, fc2_b, (float*)d_out, N, OUT);
}

// Round 12
// 464.284 us; speedup vs baseline: 1.5984x; 1.1171x over previous
//
#include <hip/hip_runtime.h>

#define H 128

typedef __attribute__((ext_vector_type(8))) short bf16x8;
typedef __attribute__((ext_vector_type(4))) float f32x4;

__device__ __forceinline__ float bf2f(unsigned short u) {
    return __uint_as_float(((unsigned)u) << 16);
}
__device__ __forceinline__ unsigned short f2bf(float f) {
    unsigned u = __float_as_uint(f);
    unsigned r = (u + 0x7fffu + ((u >> 16) & 1u)) >> 16;
    return (unsigned short)r;
}
__device__ __forceinline__ unsigned pack2bf(float a, float b) {
    return (unsigned)f2bf(a) | ((unsigned)f2bf(b) << 16);
}

__global__ void fill_u32(unsigned* __restrict__ p, unsigned v, int n) {
    int i = blockIdx.x * blockDim.x + threadIdx.x;
    if (i < n) p[i] = v;
}

// ---------------- fuse: MFMA K=32, bf16 out ----------------
// sat = relu(x[:, :32] @ sat_w^T); nei = relu(x[:, 32:] @ neigh_w^T); gate; h0b bf16.
__global__ void fuse_kernel(const float* __restrict__ x,
                            const float* __restrict__ sat_w, const float* __restrict__ sat_b,
                            const float* __restrict__ neigh_w, const float* __restrict__ neigh_b,
                            const float* __restrict__ fus_w, const float* __restrict__ fus_b,
                            unsigned short* __restrict__ h0b, int N) {
    __shared__ unsigned smem[8512]; // union: [a_lds 64x36 | w_lds 256x20] then cst 64x266 bf16
    __shared__ float reds[4][64];
    unsigned* a_lds = smem;          // [node][kp] kp<32, stride 36
    unsigned* w_lds = smem + 2304;   // [feat(0..127 sat,128..255 nei)][kp] kp<16, stride 20
    int tid = threadIdx.x;
    int base = blockIdx.x * 64;
    for (int i = tid; i < 64 * 32; i += 256) {
        int n = i >> 5, kp = i & 31;
        int gn = base + n;
        float2 v = (gn < N) ? *(const float2*)(x + (size_t)gn * 64 + kp * 2) : make_float2(0.f, 0.f);
        a_lds[n * 36 + kp] = pack2bf(v.x, v.y);
    }
    for (int i = tid; i < 256 * 16; i += 256) {
        int r = i >> 4, kp = i & 15;
        const float* wsrc = (r < 128) ? (sat_w + (size_t)r * 32) : (neigh_w + (size_t)(r - 128) * 32);
        float2 v = *(const float2*)(wsrc + kp * 2);
        w_lds[r * 20 + kp] = pack2bf(v.x, v.y);
    }
    __syncthreads();
    int lane = tid & 63;
    int wv = tid >> 6;
    int lr = lane & 15, lk = lane >> 4;
    f32x4 accS[4][2], accN[4][2];
#pragma unroll
    for (int r = 0; r < 4; ++r)
#pragma unroll
        for (int t = 0; t < 2; ++t) {
            accS[r][t] = (f32x4){0.f, 0.f, 0.f, 0.f};
            accN[r][t] = (f32x4){0.f, 0.f, 0.f, 0.f};
        }
    bf16x8 afS[4], afN[4];
#pragma unroll
    for (int r = 0; r < 4; ++r) {
        afS[r] = *(const bf16x8*)&a_lds[(r * 16 + lr) * 36 + lk * 4];
        afN[r] = *(const bf16x8*)&a_lds[(r * 16 + lr) * 36 + 16 + lk * 4];
    }
#pragma unroll
    for (int t = 0; t < 2; ++t) {
        bf16x8 bS = *(const bf16x8*)&w_lds[(wv * 32 + t * 16 + lr) * 20 + lk * 4];
        bf16x8 bN = *(const bf16x8*)&w_lds[(128 + wv * 32 + t * 16 + lr) * 20 + lk * 4];
#pragma unroll
        for (int r = 0; r < 4; ++r) {
            accS[r][t] = __builtin_amdgcn_mfma_f32_16x16x32_bf16(afS[r], bS, accS[r][t], 0, 0, 0);
            accN[r][t] = __builtin_amdgcn_mfma_f32_16x16x32_bf16(afN[r], bN, accN[r][t], 0, 0, 0);
        }
    }
    __syncthreads(); // a_lds/w_lds reads complete before cst overwrite
    unsigned short* cst = (unsigned short*)smem; // [64][266]: sat cols 0..127, nei at 133+col
#pragma unroll
    for (int t = 0; t < 2; ++t) {
        int col = wv * 32 + t * 16 + lr;
        float sb = sat_b[col], nb = neigh_b[col];
#pragma unroll
        for (int r = 0; r < 4; ++r) {
#pragma unroll
            for (int j = 0; j < 4; ++j) {
                int srow = r * 16 + lk * 4 + j;
                cst[srow * 266 + col] = f2bf(fmaxf(accS[r][t][j] + sb, 0.f));
                cst[srow * 266 + 133 + col] = f2bf(fmaxf(accN[r][t][j] + nb, 0.f));
            }
        }
    }
    __syncthreads();
    int node = tid & 63;
    int part = tid >> 6;
    float ps = 0.f;
#pragma unroll
    for (int k = 0; k < 32; ++k) {
        int col = part * 32 + k;
        ps += bf2f(cst[node * 266 + col]) * fus_w[col]
            + bf2f(cst[node * 266 + 133 + col]) * fus_w[128 + col];
    }
    reds[part][node] = ps;
    __syncthreads();
    float tot = reds[0][node] + reds[1][node] + reds[2][node] + reds[3][node];
    float g = 1.f / (1.f + __expf(-(tot + fus_b[0])));
    if (base + node < N) {
        unsigned* op = (unsigned*)h0b + (size_t)(base + node) * 64 + part * 16;
#pragma unroll
        for (int kp = 0; kp < 16; ++kp) {
            int col = part * 32 + kp * 2;
            float o0 = g * bf2f(cst[node * 266 + col]) + (1.f - g) * bf2f(cst[node * 266 + 133 + col]);
            float o1 = g * bf2f(cst[node * 266 + col + 1]) + (1.f - g) * bf2f(cst[node * 266 + 134 + col]);
            op[kp] = pack2bf(o0, o1);
        }
    }
}

// ---------------- MFMA bf16 GEMM: 64 nodes x 128 cols per block ----------------
template <int TAG, int IBF16>
__global__ void gemm128m(const void* __restrict__ inv, const float* __restrict__ w,
                         const float* __restrict__ bias, int do_relu,
                         unsigned short* __restrict__ outb, int N,
                         const float* __restrict__ a_sp, const float* __restrict__ a_dp,
                         float* __restrict__ al_s, float* __restrict__ al_d) {
    __shared__ unsigned a_lds[64 * 68];
    __shared__ unsigned w_lds[128 * 68];
    __shared__ float reds[4][64];
    __shared__ float redd[4][64];
    int tid = threadIdx.x;
    int base = blockIdx.x * 64;
    for (int i = tid; i < 64 * 64; i += 256) {
        int n = i >> 6, kp = i & 63;
        int gn = base + n;
        if (IBF16) {
            a_lds[n * 68 + kp] = (gn < N) ? ((const unsigned*)inv)[(size_t)gn * 64 + kp] : 0u;
        } else {
            float2 v = (gn < N) ? *(const float2*)((const float*)inv + (size_t)gn * 128 + kp * 2)
                                : make_float2(0.f, 0.f);
            a_lds[n * 68 + kp] = pack2bf(v.x, v.y);
        }
    }
    for (int i = tid; i < 128 * 64; i += 256) {
        int c = i >> 6, kp = i & 63;
        float2 v = *(const float2*)(w + (size_t)c * 128 + kp * 2);
        w_lds[c * 68 + kp] = pack2bf(v.x, v.y);
    }
    __syncthreads();
    int lane = tid & 63;
    int wv = tid >> 6;
    int lr = lane & 15;
    int lk = lane >> 4;
    f32x4 acc[4][2];
#pragma unroll
    for (int r = 0; r < 4; ++r)
#pragma unroll
        for (int t = 0; t < 2; ++t) acc[r][t] = (f32x4){0.f, 0.f, 0.f, 0.f};
    for (int c = 0; c < 4; ++c) {
        bf16x8 af[4], bfr[2];
#pragma unroll
        for (int r = 0; r < 4; ++r)
            af[r] = *(const bf16x8*)&a_lds[(r * 16 + lr) * 68 + c * 16 + lk * 4];
#pragma unroll
        for (int t = 0; t < 2; ++t)
            bfr[t] = *(const bf16x8*)&w_lds[(wv * 32 + t * 16 + lr) * 68 + c * 16 + lk * 4];
#pragma unroll
        for (int r = 0; r < 4; ++r)
#pragma unroll
            for (int t = 0; t < 2; ++t)
                acc[r][t] = __builtin_amdgcn_mfma_f32_16x16x32_bf16(af[r], bfr[t], acc[r][t], 0, 0, 0);
    }
    __syncthreads();
    unsigned short* cst = (unsigned short*)a_lds; // [64][136]
#pragma unroll
    for (int t = 0; t < 2; ++t) {
        int col = wv * 32 + t * 16 + lr;
        float bv = bias ? bias[col] : 0.f;
#pragma unroll
        for (int r = 0; r < 4; ++r) {
#pragma unroll
            for (int j = 0; j < 4; ++j) {
                float v = acc[r][t][j] + bv;
                if (do_relu) v = fmaxf(v, 0.f);
                cst[(r * 16 + lk * 4 + j) * 136 + col] = f2bf(v);
            }
        }
    }
    __syncthreads();
    for (int i = tid; i < 64 * 64; i += 256) {
        int n = i >> 6, kp = i & 63;
        int gn = base + n;
        if (gn < N) ((unsigned*)outb)[(size_t)gn * 64 + kp] = a_lds[n * 68 + kp];
    }
    if (a_sp) {
        int node = tid & 63;
        int part = tid >> 6;
        float ps = 0.f, pd = 0.f;
        int kb = part * 32;
        const unsigned short* xr = cst + node * 136 + kb;
#pragma unroll
        for (int k = 0; k < 32; ++k) {
            float v = bf2f(xr[k]);
            ps += v * a_sp[kb + k];
            pd += v * a_dp[kb + k];
        }
        reds[part][node] = ps;
        redd[part][node] = pd;
        __syncthreads();
        if (tid < 64) {
            int gn = base + tid;
            if (gn < N) {
                al_s[gn] = reds[0][tid] + reds[1][tid] + reds[2][tid] + reds[3][tid];
                al_d[gn] = redd[0][tid] + redd[1][tid] + redd[2][tid] + redd[3][tid];
            }
        }
    }
}

// ---------------- packed edge list (requires N <= 65536; here N=50000) ----------------
#define SCB 256
__global__ void pack_edges(const int* __restrict__ src, const int* __restrict__ dst,
                           unsigned* __restrict__ pk, int E) {
    int e = blockIdx.x * blockDim.x + threadIdx.x;
    if (e < E) pk[e] = ((unsigned)dst[e] << 16) | (unsigned)src[e];
}

__global__ void hist8(const unsigned* __restrict__ pk, int* __restrict__ cnt, int E, int N) {
    int g = blockIdx.x & 7;
    int chunk = blockIdx.x >> 3;
    int nch = gridDim.x >> 3;
    int NR = (N + 7) >> 3;
    int lo = g * NR;
    int hi = min(lo + NR, N);
    for (int e = chunk * SCB + threadIdx.x; e < E; e += nch * SCB) {
        int d = (int)(pk[e] >> 16);
        if (d >= lo && d < hi) atomicAdd(cnt + d, 1);
    }
}

__global__ void scan_a(const int* __restrict__ cnt, int* __restrict__ nodeoff,
                       int* __restrict__ blocksum, int N) {
    int i = blockIdx.x * SCB + threadIdx.x;
    int tot = (i < N) ? cnt[i] : 0;
    __shared__ int tmp[SCB];
    tmp[threadIdx.x] = tot;
    __syncthreads();
    for (int off = 1; off < SCB; off <<= 1) {
        int t = (threadIdx.x >= off) ? tmp[threadIdx.x - off] : 0;
        __syncthreads();
        tmp[threadIdx.x] += t;
        __syncthreads();
    }
    if (i < N) nodeoff[i] = tmp[threadIdx.x] - tot;
    if (threadIdx.x == SCB - 1) blocksum[blockIdx.x] = tmp[SCB - 1];
}

__global__ void scan_b(const int* __restrict__ blocksum, int* __restrict__ blockoff,
                       int* __restrict__ rowptrN, int NB) {
    __shared__ int tmp[1024];
    int t = threadIdx.x;
    int v = (t < NB) ? blocksum[t] : 0;
    tmp[t] = v;
    __syncthreads();
    for (int off = 1; off < 1024; off <<= 1) {
        int u = (t >= off) ? tmp[t - off] : 0;
        __syncthreads();
        tmp[t] += u;
        __syncthreads();
    }
    if (t < NB) blockoff[t] = tmp[t] - v;
    if (t == 1023) *rowptrN = tmp[1023];
}

__global__ void scan_c(const int* __restrict__ nodeoff, const int* __restrict__ blockoff,
                       int* __restrict__ rowptr, int* __restrict__ cursor,
                       float* __restrict__ accum2, int N) {
    if (blockIdx.x < 2) {
        accum2[blockIdx.x * 256 + threadIdx.x] = 0.f;
    }
    int i = blockIdx.x * SCB + threadIdx.x;
    if (i >= N) return;
    int run = blockoff[blockIdx.x] + nodeoff[i];
    rowptr[i] = run;
    cursor[i] = run;
}

__global__ void scatter8(const unsigned* __restrict__ pk, int* __restrict__ cursor,
                         int* __restrict__ ssrc, int E, int N) {
    int g = blockIdx.x & 7;
    int chunk = blockIdx.x >> 3;
    int nch = gridDim.x >> 3;
    int NR = (N + 7) >> 3;
    int lo = g * NR;
    int hi = min(lo + NR, N);
    for (int e = chunk * SCB + threadIdx.x; e < E; e += nch * SCB) {
        unsigned p = pk[e];
        int d = (int)(p >> 16);
        if (d >= lo && d < hi) {
            int pos = atomicAdd(cursor + d, 1);
            ssrc[pos] = (int)(p & 0xFFFFu);
        }
    }
}

// ---------------- GAT aggregation: one wave per dst node, bf16 h ----------------
#define PF 8
template <int TAG>
__global__ void gat_agg(const int* __restrict__ rowptr, const int* __restrict__ ssrc,
                        const float* __restrict__ al_s, const float* __restrict__ al_d,
                        const unsigned short* __restrict__ hb, float* __restrict__ out, int N) {
    __shared__ int s_sv[4][64];
    __shared__ float s_ev[4][64];
    int wiw = threadIdx.x >> 6;
    int w = (blockIdx.x * blockDim.x + threadIdx.x) >> 6;
    int lane = threadIdx.x & 63;
    if (w >= N) return;
    int beg = rowptr[w], end = rowptr[w + 1];
    float ald = al_d[w];
    float a_self = al_s[w] + ald;
    a_self = (a_self > 0.f) ? a_self : 0.2f * a_self;
    float m = a_self;
    for (int e = beg + lane; e < end; e += 64) {
        float a = al_s[ssrc[e]] + ald;
        a = (a > 0.f) ? a : 0.2f * a;
        m = fmaxf(m, a);
    }
    for (int off = 32; off; off >>= 1) m = fmaxf(m, __shfl_xor(m, off));
    float ss = 0.f, acc0 = 0.f, acc1 = 0.f;
    for (int base = beg; base < end; base += 64) {
        int nch = min(64, end - base);
        int sv = 0;
        float ev = 0.f;
        if (lane < nch) {
            sv = ssrc[base + lane];
            float a = al_s[sv] + ald;
            a = (a > 0.f) ? a : 0.2f * a;
            ev = __expf(a - m);
        }
        ss += ev;
        s_sv[wiw][lane] = sv;
        s_ev[wiw][lane] = ev;
        for (int j0 = 0; j0 < nch; j0 += PF) {
            int np = min(PF, nch - j0);
            ushort2 hv[PF];
#pragma unroll
            for (int jj = 0; jj < PF; ++jj) {
                if (jj < np) {
                    int svj = s_sv[wiw][j0 + jj];
                    hv[jj] = ((const ushort2*)(hb + (size_t)svj * H))[lane];
                }
            }
#pragma unroll
            for (int jj = 0; jj < PF; ++jj) {
                if (jj < np) {
                    float evj = s_ev[wiw][j0 + jj];
                    acc0 += evj * bf2f(hv[jj].x);
                    acc1 += evj * bf2f(hv[jj].y);
                }
            }
        }
    }
    for (int off = 32; off; off >>= 1) ss += __shfl_xor(ss, off);
    float ev_self = __expf(a_self - m);
    ss += ev_self;
    ushort2 hs = ((const ushort2*)(hb + (size_t)w * H))[lane];
    acc0 += ev_self * bf2f(hs.x);
    acc1 += ev_self * bf2f(hs.y);
    float inv = 1.f / (ss + 1e-16f);
    ((float2*)(out + (size_t)w * H))[lane] = make_float2(acc0 * inv, acc1 * inv);
}

// ---------------- BN stats ----------------
__global__ void bn_stats(const float* __restrict__ y, float* __restrict__ accum, int N) {
    int f = threadIdx.x & 127;
    int half = threadIdx.x >> 7;
    float sum = 0.f, sumsq = 0.f;
    for (int n = blockIdx.x * 2 + half; n < N; n += gridDim.x * 2) {
        float v = y[(size_t)n * H + f];
        sum += v;
        sumsq += v * v;
    }
    __shared__ float ls[2][128], ls2[2][128];
    ls[half][f] = sum;
    ls2[half][f] = sumsq;
    __syncthreads();
    if (half == 0) {
        atomicAdd(accum + f, ls[0][f] + ls[1][f]);
        atomicAdd(accum + 128 + f, ls2[0][f] + ls2[1][f]);
    }
}

// ---------------- BN apply + relu + residual (res fp32 or bf16) ----------------
template <int RESBF>
__global__ void bn_apply(float* __restrict__ y, const float* __restrict__ accum,
                         const float* __restrict__ g, const float* __restrict__ be,
                         const void* __restrict__ res, int N) {
    int i = blockIdx.x * blockDim.x + threadIdx.x;
    if (i >= N * H) return;
    int f = i & 127;
    float Ninv = 1.f / (float)N;
    float mu = accum[f] * Ninv;
    float var = accum[128 + f] * Ninv - mu * mu;
    float v = (y[i] - mu) * rsqrtf(var + 1e-5f) * g[f] + be[f];
    float r = RESBF ? bf2f(((const unsigned short*)res)[i]) : ((const float*)res)[i];
    y[i] = fmaxf(v, 0.f) + r;
}

// ---------------- final fc2: bf16 input rows staged in LDS ----------------
__global__ void fc2_kernel(const unsigned short* __restrict__ in, const float* __restrict__ w,
                           const float* __restrict__ b, float* __restrict__ out,
                           int N, int OUT) {
    __shared__ float wsm[16 * 132];
    __shared__ float xs[16][129];
    int tid = threadIdx.x;
    for (int i = tid; i < OUT * H; i += 256) {
        int o = i >> 7, k = i & 127;
        wsm[o * 132 + k] = w[i];
    }
    int nb = blockIdx.x * 16;
    for (int i = tid; i < 16 * 128; i += 256) {
        int n = i >> 7, k = i & 127;
        int gn = nb + n;
        xs[n][k] = (gn < N) ? bf2f(in[(size_t)gn * H + k]) : 0.f;
    }
    __syncthreads();
    int o = tid & 15;
    int nn = tid >> 4;
    int n = nb + nn;
    if (n >= N || o >= OUT) return;
    const float* xr = xs[nn];
    const float* wr = wsm + o * 132;
    float acc = b[o];
#pragma unroll 8
    for (int k = 0; k < H; k += 4) {
        acc += xr[k] * wr[k] + xr[k + 1] * wr[k + 1] + xr[k + 2] * wr[k + 2] + xr[k + 3] * wr[k + 3];
    }
    out[(size_t)n * OUT + o] = acc;
}

// ---------------- launch ----------------

extern "C" void kernel_launch(void* const* d_in, const int* in_sizes, int n_in,
                              void* d_out, int out_size, void* d_ws, size_t ws_size,
                              hipStream_t stream) {
    const float* x       = (const float*)d_in[0];
    const int*   ei      = (const int*)d_in[1];
    const float* sat_w   = (const float*)d_in[2];
    const float* sat_b   = (const float*)d_in[3];
    const float* neigh_w = (const float*)d_in[4];
    const float* neigh_b = (const float*)d_in[5];
    const float* fus_w   = (const float*)d_in[6];
    const float* fus_b   = (const float*)d_in[7];
    const float* w1      = (const float*)d_in[8];
    const float* as1     = (const float*)d_in[9];
    const float* ad1     = (const float*)d_in[10];
    const float* g1      = (const float*)d_in[12];
    const float* be1     = (const float*)d_in[13];
    const float* w2      = (const float*)d_in[14];
    const float* as2     = (const float*)d_in[15];
    const float* ad2     = (const float*)d_in[16];
    const float* g2      = (const float*)d_in[18];
    const float* be2     = (const float*)d_in[19];
    const float* fc1_w   = (const float*)d_in[20];
    const float* fc1_b   = (const float*)d_in[21];
    const float* fc2_w   = (const float*)d_in[22];
    const float* fc2_b   = (const float*)d_in[23];

    int N = in_sizes[0] / 64;
    int E = in_sizes[1] / 2;
    int OUT = in_sizes[23];
    int NB = (N + SCB - 1) / SCB;

    float* ws    = (float*)d_ws;
    float* h0    = ws;                      // N*H fp32 (layer2 gat out / bn in-place)
    float* hA    = h0 + (size_t)N * H;      // N*H region: lower half = gemm bf16 out, upper half = fuse bf16 out
    float* agg   = hA + (size_t)N * H;      // N*H fp32 (layer1 gat out / bn in-place)
    float* al_s  = agg + (size_t)N * H;     // N
    float* al_d  = al_s + N;                // N
    float* accum = al_d + N;                // 512
    int* rowptr  = (int*)(accum + 512);     // N+1
    int* cnt     = rowptr + (N + 1);        // N
    int* cursor  = cnt + N;                 // N
    int* nodeoff = cursor + N;              // N
    int* blocksum= nodeoff + N;             // NB
    int* blockoff= blocksum + NB;           // NB
    int* ssrc    = blockoff + NB;           // E
    unsigned* pk = (unsigned*)(ssrc + E);   // E
    unsigned short* hAb = (unsigned short*)hA;
    unsigned short* h0b = (unsigned short*)(hA + (size_t)N * 64);

    const int* srcp = ei;
    const int* dstp = ei + E;

    dim3 b256(256);
    int gGemm = (N + 63) / 64;
    int gNH = (N * H + 255) / 256;
    int gWaveN = (N + 3) / 4;
    int gOwn = 512 * 8;

    // ---- fuse (bf16 out) ----
    fuse_kernel<<<gGemm, b256, 0, stream>>>(x, sat_w, sat_b, neigh_w, neigh_b, fus_w, fus_b, h0b, N);

    // ---- CSR build (packed edges, XCD-ownership) ----
    pack_edges<<<(E + 255) / 256, b256, 0, stream>>>(srcp, dstp, pk, E);
    fill_u32<<<(N + 255) / 256, b256, 0, stream>>>((unsigned*)cnt, 0u, N);
    hist8<<<gOwn, b256, 0, stream>>>(pk, cnt, E, N);
    scan_a<<<NB, SCB, 0, stream>>>(cnt, nodeoff, blocksum, N);
    scan_b<<<1, 1024, 0, stream>>>(blocksum, blockoff, rowptr + N, NB);
    scan_c<<<NB, SCB, 0, stream>>>(nodeoff, blockoff, rowptr, cursor, accum, N);
    scatter8<<<gOwn, b256, 0, stream>>>(pk, cursor, ssrc, E, N);

    // ================= GAT layer 1 =================
    gemm128m<1, 1><<<gGemm, b256, 0, stream>>>(h0b, w1, nullptr, 0, hAb, N, as1, ad1, al_s, al_d);
    gat_agg<1><<<gWaveN, b256, 0, stream>>>(rowptr, ssrc, al_s, al_d, hAb, agg, N);
    bn_stats<<<512, b256, 0, stream>>>(agg, accum, N);
    bn_apply<1><<<gNH, b256, 0, stream>>>(agg, accum, g1, be1, h0b, N);

    // ================= GAT layer 2 =================
    gemm128m<2, 0><<<gGemm, b256, 0, stream>>>(agg, w2, nullptr, 0, hAb, N, as2, ad2, al_s, al_d);
    gat_agg<2><<<gWaveN, b256, 0, stream>>>(rowptr, ssrc, al_s, al_d, hAb, h0, N);
    bn_stats<<<512, b256, 0, stream>>>(h0, accum + 256, N);
    bn_apply<0><<<gNH, b256, 0, stream>>>(h0, accum + 256, g2, be2, agg, N);

    // ================= head =================
    gemm128m<3, 0><<<gGemm, b256, 0, stream>>>(h0, fc1_w, fc1_b, 1, hAb, N, nullptr, nullptr, nullptr, nullptr);
    fc2_kernel<<<(N + 15) / 16, b256, 0, stream>>>(hAb, fc2_w, fc2_b, (float*)d_out, N, OUT);
}